// Round 17
// baseline (133.716 us; speedup 1.0000x reference)
//
#include <hip/hip_runtime.h>
#include <hip/hip_bf16.h>
#include <stdint.h>

#define NB   16
#define CIN  2048
#define OUTC 256
#define HW   1024
#define BJ   64
#define BK   64
#define NJT  (HW / BJ)          // 16 j-tiles
#define KSTEPS (CIN / BK)       // 32 steps of 64 k

typedef __attribute__((ext_vector_type(8))) short bf16x8;
typedef __attribute__((ext_vector_type(4))) float f32x4;
typedef __attribute__((ext_vector_type(4))) unsigned int u32x4;

__device__ __forceinline__ unsigned int f2bf(float f) {
    union { float f; unsigned int u; } a; a.f = f;
    return (a.u + 0x7FFFu + ((a.u >> 16) & 1u)) >> 16;  // RNE
}

// Raw barrier: drains LDS ops only; global prefetch loads stay in flight.
__device__ __forceinline__ void block_sync_lds() {
    asm volatile("s_waitcnt lgkmcnt(0)" ::: "memory");
    __builtin_amdgcn_s_barrier();
    asm volatile("" ::: "memory");
}

// ---- kernel 1 (fused W-prep + GEMM):
//  preamble: this block converts Afrag slice (blk & 63) [16 KB, 4 redundant
//  identical writers], fence+flag; polls all 64 flags overlapped with its own
//  cold LDB(0); then the proven R14 loop. Deadlock-free: flag-set precedes
//  any wait, no cross-block dependency before the set.
__global__ __launch_bounds__(512, 2) void gemm_stats_kernel(
    const float* __restrict__ x,             // [16][2048][1024]
    const float* __restrict__ W,             // [256][2048]
    unsigned short* __restrict__ Afrag,      // ws: 1 MiB
    unsigned int* __restrict__ flags,        // ws: 64 (pre-zeroed per call)
    float* __restrict__ s1_part,             // [NJT][NB][OUTC]
    float* __restrict__ s2_part)             // [256][OUTC]
{
    __shared__ __align__(16) unsigned short B0[4096], B1[4096]; // 8 KB each
    __shared__ __align__(16) unsigned short PAD[40960];         // 80 KB occupancy fence

    const int tid  = threadIdx.x;
    const int lane = tid & 63;
    const int wave = tid >> 6;
    const int blk  = blockIdx.x;   // 0..255
    const int n    = blk >> 4;
    const int jt   = blk & 15;
    const int j0   = jt * BJ;

    // ---- phase A: convert slice s = blk & 63 (ks32 = s) into Afrag ----
    {
        const int s = blk & 63;
        #pragma unroll
        for (int half = 0; half < 2; ++half) {
            int task = half * 512 + tid;       // 1024 tasks: (ot, l)
            int ot = task >> 6;
            int l  = task & 63;
            const float4* p = reinterpret_cast<const float4*>(
                W + (ot * 16 + (l & 15)) * CIN + 32 * s + (l >> 4) * 8);
            float4 v0 = p[0], v1 = p[1];
            u32x4 pk;
            pk.x = f2bf(v0.x) | (f2bf(v0.y) << 16);
            pk.y = f2bf(v0.z) | (f2bf(v0.w) << 16);
            pk.z = f2bf(v1.x) | (f2bf(v1.y) << 16);
            pk.w = f2bf(v1.z) | (f2bf(v1.w) << 16);
            *reinterpret_cast<u32x4*>(Afrag + (((size_t)s * 16 + ot) * 64 + l) * 8) = pk;
        }
        __threadfence();
        __syncthreads();
        if (tid == 0) atomicAdd(&flags[s], 1u);
    }

    const float* xn = x + (size_t)n * CIN * HW;

    const int bj = tid & 63;
    const int kh = tid >> 6;
    const float* Bgp = xn + (size_t)(kh * 8) * HW + j0 + bj;
    const int offB = (kh >> 2) * 2048 + (bj >> 4) * 512 + (kh & 3) * 128 + (bj & 15) * 8;

    const int rbase = lane * 8;    // fragment-linear read base (+ h*2048 + ni*512)
    const unsigned short* Ab = Afrag + (size_t)lane * 8;

#define CLMP(v) (((v) < KSTEPS) ? (v) : KSTEPS - 1)
#define LDA(ks, R) { _Pragma("unroll") \
    for (int h = 0; h < 2; ++h) _Pragma("unroll") for (int t = 0; t < 2; ++t) \
        R[h * 2 + t] = *(const u32x4*)(Ab + ((((ks) * 2 + h) * 16 + 2 * wave + t) * 64) * 8); }
#define LDB(ks, F) { const float* p = Bgp + (size_t)(ks) * BK * HW; \
    _Pragma("unroll") for (int i = 0; i < 8; ++i) F[i] = p[(size_t)i * HW]; }
#define WRITEB(Bb, F) { u32x4 pk; \
    pk.x = f2bf(F[0]) | (f2bf(F[1]) << 16); pk.y = f2bf(F[2]) | (f2bf(F[3]) << 16); \
    pk.z = f2bf(F[4]) | (f2bf(F[5]) << 16); pk.w = f2bf(F[6]) | (f2bf(F[7]) << 16); \
    *(u32x4*)&Bb[offB] = pk; }
#define COMPUTE(Bb, R) { _Pragma("unroll") \
    for (int h = 0; h < 2; ++h) { \
        bf16x8 af0 = *(const bf16x8*)&R[h * 2 + 0]; \
        bf16x8 af1 = *(const bf16x8*)&R[h * 2 + 1]; \
        _Pragma("unroll") \
        for (int ni = 0; ni < 4; ++ni) { \
            bf16x8 bf = *(const bf16x8*)&Bb[h * 2048 + ni * 512 + rbase]; \
            acc[0][ni] = __builtin_amdgcn_mfma_f32_16x16x32_bf16(af0, bf, acc[0][ni], 0, 0, 0); \
            acc[1][ni] = __builtin_amdgcn_mfma_f32_16x16x32_bf16(af1, bf, acc[1][ni], 0, 0, 0); \
    } } }

    f32x4 acc[2][4] = {};
    u32x4 Aa0[4], Aa1[4];      // A reg sets: Aa0 <-> even steps (B0), Aa1 <-> odd (B1)
    float BsA[8], BsB[8];

    // prologue: issue cold B loads first (HBM latency covers the flag poll)
    LDB(0, BsA);
    LDB(1, BsB);
    // poll all 64 slice flags (overlapped with the in-flight LDB misses)
    if (tid < 64) {
        while (__hip_atomic_load(&flags[tid], __ATOMIC_RELAXED,
                                 __HIP_MEMORY_SCOPE_AGENT) == 0u)
            __builtin_amdgcn_s_sleep(2);
    }
    __syncthreads();
    __threadfence();                           // acquire: Afrag visible
    LDA(0, Aa0);
    LDA(1, Aa1);
    WRITEB(B0, BsA);
    LDB(2, BsA);
    block_sync_lds();

    #pragma unroll 1
    for (int ks = 0; ks < KSTEPS; ks += 2) {
        // even step: compute B0 / Aa0
        COMPUTE(B0, Aa0);
        {
            LDA(CLMP(ks + 2), Aa0);
            WRITEB(B1, BsB);               // stage data ks+1
            LDB(CLMP(ks + 3), BsB);
            block_sync_lds();
        }
        // odd step: compute B1 / Aa1
        COMPUTE(B1, Aa1);
        {
            LDA(CLMP(ks + 3), Aa1);
        }
        if (ks + 2 < KSTEPS) {
            WRITEB(B0, BsA);               // stage data ks+2
            LDB(CLMP(ks + 4), BsA);
            block_sync_lds();
        }
    }

    // ---- epilogue: per-channel sum / sum-of-squares over this block's 64 j ----
    // C/D layout: col(j) = lane&15, row = (lane>>4)*4 + r  [m89]
    float rs[2][4], rq[2][4];
    #pragma unroll
    for (int mi = 0; mi < 2; ++mi)
        #pragma unroll
        for (int r = 0; r < 4; ++r) {
            float s = 0.f, q = 0.f;
            #pragma unroll
            for (int ni = 0; ni < 4; ++ni) {
                float v = acc[mi][ni][r];
                s += v; q += v * v;
            }
            rs[mi][r] = s; rq[mi][r] = q;
        }
    #pragma unroll
    for (int m = 1; m < 16; m <<= 1)
        #pragma unroll
        for (int mi = 0; mi < 2; ++mi)
            #pragma unroll
            for (int r = 0; r < 4; ++r) {
                rs[mi][r] += __shfl_xor(rs[mi][r], m, 64);
                rq[mi][r] += __shfl_xor(rq[mi][r], m, 64);
            }
    if ((lane & 15) == 0) {
        const int gK = lane >> 4;
        #pragma unroll
        for (int mi = 0; mi < 2; ++mi)
            #pragma unroll
            for (int r = 0; r < 4; ++r) {
                int o = wave * 32 + mi * 16 + gK * 4 + r;
                s1_part[(jt * NB + n) * OUTC + o] = rs[mi][r];
                s2_part[blk * OUTC + o]           = rq[mi][r];
            }
    }

    // keep PAD alive (never executes: x is never (const float*)1)
    if (__builtin_expect((uintptr_t)x == 1, 0)) {
        PAD[tid] = (unsigned short)tid;
        __syncthreads();
        ((volatile unsigned short*)B0)[0] = PAD[(tid * 131) & 40959];
    }
#undef CLMP
#undef LDA
#undef LDB
#undef WRITEB
#undef COMPUTE
}

// ---- kernel 2 (fused finalize+broadcast): block = (n, 16 channels). ----
__global__ __launch_bounds__(256) void finalize_bcast_kernel(
    const float* __restrict__ s1_part,   // [NJT][NB][OUTC]
    const float* __restrict__ s2_part,   // [256][OUTC]
    const float* __restrict__ gamma,
    const float* __restrict__ beta,
    float* __restrict__ out)             // [NB][OUTC][1024]
{
    const int tid   = threadIdx.x;
    const int slice = tid & 15;
    const int o_l   = tid >> 4;
    const int n0    = blockIdx.x >> 4;
    const int o     = (blockIdx.x & 15) * 16 + o_l;

    float S1 = 0.f, S2 = 0.f;
    #pragma unroll
    for (int q = 0; q < 16; ++q) {
        int p = slice * 16 + q;          // covers all 256 partials
        S1 += s1_part[p * OUTC + o];
        S2 += s2_part[p * OUTC + o];
    }
    float s1n = s1_part[(slice * NB + n0) * OUTC + o];   // jt = slice
    #pragma unroll
    for (int m = 1; m < 16; m <<= 1) {
        S1  += __shfl_xor(S1, m, 64);
        S2  += __shfl_xor(S2, m, 64);
        s1n += __shfl_xor(s1n, m, 64);
    }
    float mean = S1 * (1.f / 16384.f);
    float var  = S2 * (1.f / 16384.f) - mean * mean;   // biased var (matches ref)
    float inv  = rsqrtf(var + 1e-5f);
    float v = gamma[o] * (s1n * (1.f / 1024.f) - mean) * inv + beta[o];

    float4 vv = make_float4(v, v, v, v);
    float4* dst = reinterpret_cast<float4*>(out + ((size_t)(n0 * OUTC + o)) * HW);
    #pragma unroll
    for (int it = 0; it < 16; ++it)
        dst[it * 16 + slice] = vv;
}

extern "C" void kernel_launch(void* const* d_in, const int* in_sizes, int n_in,
                              void* d_out, int out_size, void* d_ws, size_t ws_size,
                              hipStream_t stream) {
    const float* x     = (const float*)d_in[0];
    const float* W     = (const float*)d_in[1];
    const float* gamma = (const float*)d_in[2];
    const float* beta  = (const float*)d_in[3];
    float* out = (float*)d_out;

    char* ws = (char*)d_ws;
    unsigned short* Afrag = (unsigned short*)ws;                 // 1 MiB
    float* s1_part = (float*)(ws + (1 << 20));                   // 256 KB
    float* s2_part = (float*)(ws + (1 << 20) + (256 << 10));     // 256 KB
    unsigned int* flags = (unsigned int*)(ws + (1 << 20) + (512 << 10)); // 256 B

    hipMemsetAsync(flags, 0, 64 * sizeof(unsigned int), stream);
    hipLaunchKernelGGL(gemm_stats_kernel, dim3(256), dim3(512), 0, stream,
                       x, W, Afrag, flags, s1_part, s2_part);
    hipLaunchKernelGGL(finalize_bcast_kernel, dim3(NB * (OUTC / 16)), dim3(256), 0, stream,
                       s1_part, s2_part, gamma, beta, out);
}

// Round 18
// 47.666 us; speedup vs baseline: 2.8053x; 2.8053x over previous
//
#include <hip/hip_runtime.h>
#include <hip/hip_bf16.h>
#include <stdint.h>

#define NB   16
#define CIN  2048
#define OUTC 256
#define HW   1024
#define BJ   64
#define BK   64
#define NJT  (HW / BJ)          // 16 j-tiles
#define KSTEPS (CIN / BK)       // 32 steps of 64 k

typedef __attribute__((ext_vector_type(8))) short bf16x8;
typedef __attribute__((ext_vector_type(4))) float f32x4;
typedef __attribute__((ext_vector_type(4))) unsigned int u32x4;

__device__ __forceinline__ unsigned int f2bf(float f) {
    union { float f; unsigned int u; } a; a.f = f;
    return (a.u + 0x7FFFu + ((a.u >> 16) & 1u)) >> 16;  // RNE
}

// Raw barrier: drains LDS ops only; global prefetch loads stay in flight.
__device__ __forceinline__ void block_sync_lds() {
    asm volatile("s_waitcnt lgkmcnt(0)" ::: "memory");
    __builtin_amdgcn_s_barrier();
    asm volatile("" ::: "memory");
}

// ---- kernel 1: W fp32 -> bf16 A-fragments in MFMA lane order. ----
__global__ void wprep_kernel(const float* __restrict__ W, unsigned short* __restrict__ Afrag) {
    int g  = blockIdx.x * blockDim.x + threadIdx.x;   // 65536
    int o  = g >> 8;
    int kc = g & 255;          // 8-k chunk within row
    const float4* p = reinterpret_cast<const float4*>(W + o * CIN + kc * 8);
    float4 v0 = p[0], v1 = p[1];
    u32x4 pk;
    pk.x = f2bf(v0.x) | (f2bf(v0.y) << 16);
    pk.y = f2bf(v0.z) | (f2bf(v0.w) << 16);
    pk.z = f2bf(v1.x) | (f2bf(v1.y) << 16);
    pk.w = f2bf(v1.z) | (f2bf(v1.w) << 16);
    int ks32 = kc >> 2, g8 = kc & 3;
    int lane = g8 * 16 + (o & 15), ot = o >> 4;
    *reinterpret_cast<u32x4*>(Afrag + (((size_t)ks32 * 16 + ot) * 64 + lane) * 8) = pk;
}

// ---- kernel 2: R14 GEMM (best known: 47.7us) with hardware bf16 pack
//      (v_cvt_pk_bf16_f32, RNE — bit-identical to f2bf) in the hot loop.
__global__ __launch_bounds__(512, 2) void gemm_stats_kernel(
    const float* __restrict__ x,             // [16][2048][1024]
    const unsigned short* __restrict__ Afrag,
    float* __restrict__ s1_part,             // [NJT][NB][OUTC]
    float* __restrict__ s2_part)             // [256][OUTC]
{
    __shared__ __align__(16) unsigned short B0[4096], B1[4096]; // 8 KB each
    __shared__ __align__(16) unsigned short PAD[40960];         // 80 KB occupancy fence
                                                                // (guarantees 1 block/CU)
    const int tid  = threadIdx.x;
    const int lane = tid & 63;
    const int wave = tid >> 6;
    const int blk  = blockIdx.x;   // 0..255
    const int n    = blk >> 4;
    const int jt   = blk & 15;
    const int j0   = jt * BJ;

    const float* xn = x + (size_t)n * CIN * HW;

    const int bj = tid & 63;
    const int kh = tid >> 6;
    const float* Bgp = xn + (size_t)(kh * 8) * HW + j0 + bj;
    const int offB = (kh >> 2) * 2048 + (bj >> 4) * 512 + (kh & 3) * 128 + (bj & 15) * 8;

    const int rbase = lane * 8;    // fragment-linear read base (+ h*2048 + ni*512)
    const unsigned short* Ab = Afrag + (size_t)lane * 8;

#define CLMP(v) (((v) < KSTEPS) ? (v) : KSTEPS - 1)
#define PK2(d, a, b) asm("v_cvt_pk_bf16_f32 %0, %1, %2" : "=v"(d) : "v"(a), "v"(b))
#define LDA(ks, R) { _Pragma("unroll") \
    for (int h = 0; h < 2; ++h) _Pragma("unroll") for (int t = 0; t < 2; ++t) \
        R[h * 2 + t] = *(const u32x4*)(Ab + ((((ks) * 2 + h) * 16 + 2 * wave + t) * 64) * 8); }
#define LDB(ks, F) { const float* p = Bgp + (size_t)(ks) * BK * HW; \
    _Pragma("unroll") for (int i = 0; i < 8; ++i) F[i] = p[(size_t)i * HW]; }
#define WRITEB(Bb, F) { u32x4 pk; \
    PK2(pk.x, F[0], F[1]); PK2(pk.y, F[2], F[3]); \
    PK2(pk.z, F[4], F[5]); PK2(pk.w, F[6], F[7]); \
    *(u32x4*)&Bb[offB] = pk; }
#define COMPUTE(Bb, R) { _Pragma("unroll") \
    for (int h = 0; h < 2; ++h) { \
        bf16x8 af0 = *(const bf16x8*)&R[h * 2 + 0]; \
        bf16x8 af1 = *(const bf16x8*)&R[h * 2 + 1]; \
        _Pragma("unroll") \
        for (int ni = 0; ni < 4; ++ni) { \
            bf16x8 bf = *(const bf16x8*)&Bb[h * 2048 + ni * 512 + rbase]; \
            acc[0][ni] = __builtin_amdgcn_mfma_f32_16x16x32_bf16(af0, bf, acc[0][ni], 0, 0, 0); \
            acc[1][ni] = __builtin_amdgcn_mfma_f32_16x16x32_bf16(af1, bf, acc[1][ni], 0, 0, 0); \
    } } }

    f32x4 acc[2][4] = {};
    u32x4 Aa0[4], Aa1[4];      // A reg sets: Aa0 <-> even steps (B0), Aa1 <-> odd (B1)
    float BsA[8], BsB[8];

    LDA(0, Aa0); LDB(0, BsA);
    LDA(1, Aa1); LDB(1, BsB);
    WRITEB(B0, BsA);
    LDB(2, BsA);
    block_sync_lds();

    #pragma unroll 1
    for (int ks = 0; ks < KSTEPS; ks += 2) {
        // even step: compute B0 / Aa0
        COMPUTE(B0, Aa0);
        {
            LDA(CLMP(ks + 2), Aa0);
            WRITEB(B1, BsB);               // stage data ks+1
            LDB(CLMP(ks + 3), BsB);
            block_sync_lds();
        }
        // odd step: compute B1 / Aa1
        COMPUTE(B1, Aa1);
        {
            LDA(CLMP(ks + 3), Aa1);
        }
        if (ks + 2 < KSTEPS) {
            WRITEB(B0, BsA);               // stage data ks+2
            LDB(CLMP(ks + 4), BsA);
            block_sync_lds();
        }
    }

    // ---- epilogue: per-channel sum / sum-of-squares over this block's 64 j ----
    // C/D layout: col(j) = lane&15, row = (lane>>4)*4 + r  [m89]
    float rs[2][4], rq[2][4];
    #pragma unroll
    for (int mi = 0; mi < 2; ++mi)
        #pragma unroll
        for (int r = 0; r < 4; ++r) {
            float s = 0.f, q = 0.f;
            #pragma unroll
            for (int ni = 0; ni < 4; ++ni) {
                float v = acc[mi][ni][r];
                s += v; q += v * v;
            }
            rs[mi][r] = s; rq[mi][r] = q;
        }
    #pragma unroll
    for (int m = 1; m < 16; m <<= 1)
        #pragma unroll
        for (int mi = 0; mi < 2; ++mi)
            #pragma unroll
            for (int r = 0; r < 4; ++r) {
                rs[mi][r] += __shfl_xor(rs[mi][r], m, 64);
                rq[mi][r] += __shfl_xor(rq[mi][r], m, 64);
            }
    if ((lane & 15) == 0) {
        const int gK = lane >> 4;
        #pragma unroll
        for (int mi = 0; mi < 2; ++mi)
            #pragma unroll
            for (int r = 0; r < 4; ++r) {
                int o = wave * 32 + mi * 16 + gK * 4 + r;
                s1_part[(jt * NB + n) * OUTC + o] = rs[mi][r];
                s2_part[blk * OUTC + o]           = rq[mi][r];
            }
    }

    // keep PAD alive (never executes: x is never (const float*)1)
    if (__builtin_expect((uintptr_t)x == 1, 0)) {
        PAD[tid] = (unsigned short)tid;
        __syncthreads();
        ((volatile unsigned short*)B0)[0] = PAD[(tid * 131) & 40959];
    }
#undef CLMP
#undef PK2
#undef LDA
#undef LDB
#undef WRITEB
#undef COMPUTE
}

// ---- kernel 3 (fused finalize+broadcast): block = (n, 16 channels). ----
__global__ __launch_bounds__(256) void finalize_bcast_kernel(
    const float* __restrict__ s1_part,   // [NJT][NB][OUTC]
    const float* __restrict__ s2_part,   // [256][OUTC]
    const float* __restrict__ gamma,
    const float* __restrict__ beta,
    float* __restrict__ out)             // [NB][OUTC][1024]
{
    const int tid   = threadIdx.x;
    const int slice = tid & 15;
    const int o_l   = tid >> 4;
    const int n0    = blockIdx.x >> 4;
    const int o     = (blockIdx.x & 15) * 16 + o_l;

    float S1 = 0.f, S2 = 0.f;
    #pragma unroll
    for (int q = 0; q < 16; ++q) {
        int p = slice * 16 + q;          // covers all 256 partials
        S1 += s1_part[p * OUTC + o];
        S2 += s2_part[p * OUTC + o];
    }
    float s1n = s1_part[(slice * NB + n0) * OUTC + o];   // jt = slice
    #pragma unroll
    for (int m = 1; m < 16; m <<= 1) {
        S1  += __shfl_xor(S1, m, 64);
        S2  += __shfl_xor(S2, m, 64);
        s1n += __shfl_xor(s1n, m, 64);
    }
    float mean = S1 * (1.f / 16384.f);
    float var  = S2 * (1.f / 16384.f) - mean * mean;   // biased var (matches ref)
    float inv  = rsqrtf(var + 1e-5f);
    float v = gamma[o] * (s1n * (1.f / 1024.f) - mean) * inv + beta[o];

    float4 vv = make_float4(v, v, v, v);
    float4* dst = reinterpret_cast<float4*>(out + ((size_t)(n0 * OUTC + o)) * HW);
    #pragma unroll
    for (int it = 0; it < 16; ++it)
        dst[it * 16 + slice] = vv;
}

extern "C" void kernel_launch(void* const* d_in, const int* in_sizes, int n_in,
                              void* d_out, int out_size, void* d_ws, size_t ws_size,
                              hipStream_t stream) {
    const float* x     = (const float*)d_in[0];
    const float* W     = (const float*)d_in[1];
    const float* gamma = (const float*)d_in[2];
    const float* beta  = (const float*)d_in[3];
    float* out = (float*)d_out;

    char* ws = (char*)d_ws;
    unsigned short* Afrag = (unsigned short*)ws;                 // 1 MiB
    float* s1_part = (float*)(ws + (1 << 20));                   // 256 KB
    float* s2_part = (float*)(ws + (1 << 20) + (256 << 10));     // 256 KB

    hipLaunchKernelGGL(wprep_kernel, dim3(256), dim3(256), 0, stream, W, Afrag);
    hipLaunchKernelGGL(gemm_stats_kernel, dim3(256), dim3(512), 0, stream,
                       x, Afrag, s1_part, s2_part);
    hipLaunchKernelGGL(finalize_bcast_kernel, dim3(NB * (OUTC / 16)), dim3(256), 0, stream,
                       s1_part, s2_part, gamma, beta, out);
}